// Round 19
// baseline (86.953 us; speedup 1.0000x reference)
//
#include <hip/hip_runtime.h>
#include <math.h>

// MX two-level fp4-e2m1 quantize->dequantize, (8192,8192) fp32.
//
// DECISION MATH FROZEN (bitwise-verified r13/r16/r17/r18, absmax=0):
//   n = RN32( RN32(x / s32) / s128 )   (subgroup scale FIRST)
//   q = sign(n) * floor(|2n| + 0.5) / 2
//   out = (q * s32) * s128;  s32 = m + 1e-8f, s128 = g + 1e-8f
// r18's provably-bitwise per-subgroup threshold (exact f64 cutoffs, ties
// impossible) kept verbatim; divide path only for s128f < 1.4 (never on
// this data) and the generic-size kernel.
//
// r19 perf change: BLOCK-CONTIGUOUS tiling. Each block owns a sequential
// 128KB segment (iters x 4KB slices) instead of grid-striding 8MB jumps ->
// every block is a purely sequential read+write DRAM stream (row-buffer
// locality, mergeable NT bursts). Coalescing per instruction unchanged;
// segment starts 256-chunk aligned so 128-elem groups stay on 32-lane
// boundaries. NT stores kept (r17: WRITE 268MB unamplified, input stays
// L3-resident).

typedef float f32x4 __attribute__((ext_vector_type(4)));

__device__ __forceinline__ float qdq_elem(float x, float s32f, float s128f) {
    float n = (x / s32f) / s128f;                 // frozen seq IEEE divides
    float q = copysignf(floorf(2.0f * fabsf(n) + 0.5f) * 0.5f, n);
    return (q * s32f) * s128f;                    // frozen dequant assoc
}

__global__ __launch_bounds__(256) void mx2q_kernel(const float* __restrict__ in,
                                                   float* __restrict__ out,
                                                   int iters) {
    const f32x4* in4 = reinterpret_cast<const f32x4*>(in);
    f32x4* out4 = reinterpret_cast<f32x4*>(out);
    // block-contiguous: block b owns chunks [b*iters*256, (b+1)*iters*256)
    int idx = (blockIdx.x * iters) * 256 + threadIdx.x;
#pragma unroll 4
    for (int it = 0; it < iters; ++it, idx += 256) {
        f32x4 v = in4[idx];
        float a = fmaxf(fmaxf(fabsf(v.x), fabsf(v.y)),
                        fmaxf(fabsf(v.z), fabsf(v.w)));
        // 32-elem subgroup = 8 consecutive lanes (4 floats/lane)
        float m = a;
        m = fmaxf(m, __shfl_xor(m, 1));
        m = fmaxf(m, __shfl_xor(m, 2));
        m = fmaxf(m, __shfl_xor(m, 4));
        // 128-elem group = 32 consecutive lanes
        float g = m;
        g = fmaxf(g, __shfl_xor(g, 8));
        g = fmaxf(g, __shfl_xor(g, 16));

        float s32f  = m + 1e-8f;
        float s128f = g + 1e-8f;

        f32x4 r;
        if (s128f >= 1.4f) {
            // per-subgroup exact threshold (all steps exact in f64)
            const double T1 = 0.25 - 3.0 / 134217728.0;   // 0.25 - 3*2^-27
            double P  = T1 * (double)s128f;               // exact (25bx24b)
            float  cf = (float)P;                         // RN32(P)
            float  c  = ((double)cf > P)
                          ? cf
                          : __uint_as_float(__float_as_uint(cf) + 1u);
            float  pc = __uint_as_float(__float_as_uint(c) - 1u);
            double t2 = 0.5 * ((double)pc + (double)c);   // exact midpoint
            double Q  = t2 * (double)s32f;                // exact (25bx24b)
            float  dq = (0.5f * s32f) * s128f;            // |out| for q=0.5

            r.x = ((double)fabsf(v.x) > Q) ? copysignf(dq, v.x)
                                           : copysignf(0.0f, v.x);
            r.y = ((double)fabsf(v.y) > Q) ? copysignf(dq, v.y)
                                           : copysignf(0.0f, v.y);
            r.z = ((double)fabsf(v.z) > Q) ? copysignf(dq, v.z)
                                           : copysignf(0.0f, v.z);
            r.w = ((double)fabsf(v.w) > Q) ? copysignf(dq, v.w)
                                           : copysignf(0.0f, v.w);
        } else {
            r.x = qdq_elem(v.x, s32f, s128f);
            r.y = qdq_elem(v.y, s32f, s128f);
            r.z = qdq_elem(v.z, s32f, s128f);
            r.w = qdq_elem(v.w, s32f, s128f);
        }
        __builtin_nontemporal_store(r, &out4[idx]);   // coalesced NT store
    }
}

// generic tail version (grid-stride, frozen divide path) for odd sizes
__global__ __launch_bounds__(256) void mx2q_kernel_gs(const float* __restrict__ in,
                                                      float* __restrict__ out,
                                                      int n4) {
    const f32x4* in4 = reinterpret_cast<const f32x4*>(in);
    f32x4* out4 = reinterpret_cast<f32x4*>(out);
    int idx = blockIdx.x * 256 + threadIdx.x;
    int stride = gridDim.x * 256;
    for (; idx < n4; idx += stride) {
        f32x4 v = in4[idx];
        float a = fmaxf(fmaxf(fabsf(v.x), fabsf(v.y)),
                        fmaxf(fabsf(v.z), fabsf(v.w)));
        float m = a;
        m = fmaxf(m, __shfl_xor(m, 1));
        m = fmaxf(m, __shfl_xor(m, 2));
        m = fmaxf(m, __shfl_xor(m, 4));
        float g = m;
        g = fmaxf(g, __shfl_xor(g, 8));
        g = fmaxf(g, __shfl_xor(g, 16));
        float s32f  = m + 1e-8f;
        float s128f = g + 1e-8f;
        f32x4 r;
        r.x = qdq_elem(v.x, s32f, s128f);
        r.y = qdq_elem(v.y, s32f, s128f);
        r.z = qdq_elem(v.z, s32f, s128f);
        r.w = qdq_elem(v.w, s32f, s128f);
        __builtin_nontemporal_store(r, &out4[idx]);
    }
}

extern "C" void kernel_launch(void* const* d_in, const int* in_sizes, int n_in,
                              void* d_out, int out_size, void* d_ws, size_t ws_size,
                              hipStream_t stream) {
    const float* x = (const float*)d_in[0];
    float* out = (float*)d_out;
    int n = in_sizes[0];              // 8192*8192 = 2^26
    int n4 = n / 4;                   // 2^24 float4 chunks
    const int blocks = 2048;          // 8 blocks/CU
    int lanes = blocks * 256;
    if (n4 % lanes == 0) {
        int iters = n4 / lanes;       // 32 for the bench shape
        hipLaunchKernelGGL(mx2q_kernel, dim3(blocks), dim3(256), 0, stream,
                           x, out, iters);
    } else {
        long long blocks_ll = ((long long)n4 + 255) / 256;
        int b = (int)(blocks_ll < 2048 ? blocks_ll : 2048);
        hipLaunchKernelGGL(mx2q_kernel_gs, dim3(b), dim3(256), 0, stream,
                           x, out, n4);
    }
}